// Round 1
// baseline (2745.100 us; speedup 1.0000x reference)
//
#include <hip/hip_runtime.h>

// Problem dims (fixed)
#define B_  2
#define T_  2048
#define C_  1024
#define H_  16
#define HS_ 64
#define FF_ 4096
#define BT_ 4096   // B_*T_

// ---------------------------------------------------------------------------
// Generic fp32 GEMM: C[m][n] = sum_k A[m*lda+k] * Belem(k,n) (+bias[n]) (+relu)
// Belem(k,n) = Bm[(n>>6)*b_os + k*ldb + (n&63)]
//   - plain row-major B[K][N]: b_os=64, ldb=N  -> k*N + n
//   - head-blocked wq/wk/wv (H,C,HS): b_os=C_*HS_, ldb=HS_ -> h*C*64 + k*64 + d
// Tile 128x128, BK=16, 256 threads, 8x8 micro-tile.
// ---------------------------------------------------------------------------
template<bool RELU, bool BIAS>
__global__ __launch_bounds__(256) void gemm_f32(
    const float* __restrict__ A, int lda,
    const float* __restrict__ Bm, int ldb, long b_os,
    float* __restrict__ Cc, int ldc,
    const float* __restrict__ bias,
    int M, int N, int K)
{
    __shared__ float As[16][132];   // As[k][m], padded (132*4B = 16B aligned, stride%32=4)
    __shared__ float Bs[16][132];   // Bs[k][n]
    const int tid = threadIdx.x;
    const int tx = tid & 15, ty = tid >> 4;
    const int m0 = blockIdx.y * 128, n0 = blockIdx.x * 128;

    float acc[8][8];
    #pragma unroll
    for (int i = 0; i < 8; i++)
        #pragma unroll
        for (int j = 0; j < 8; j++) acc[i][j] = 0.f;

    for (int k0 = 0; k0 < K; k0 += 16) {
        // A tile: 128 rows x 16 k = 512 float4, 2 per thread (transpose into As[k][m])
        #pragma unroll
        for (int i = 0; i < 2; i++) {
            int f = tid + i * 256;          // 0..511
            int r = f >> 2;                 // 0..127
            int c4 = (f & 3) * 4;           // 0,4,8,12
            float4 av = *(const float4*)&A[(long)(m0 + r) * lda + k0 + c4];
            As[c4 + 0][r] = av.x; As[c4 + 1][r] = av.y;
            As[c4 + 2][r] = av.z; As[c4 + 3][r] = av.w;
        }
        // B tile: 16 k x 128 n = 512 float4, 2 per thread
        #pragma unroll
        for (int i = 0; i < 2; i++) {
            int f = tid + i * 256;          // 0..511
            int kk = f >> 5;                // 0..15
            int n = (f & 31) * 4;           // 0..124
            int gn = n0 + n;
            float4 bv = *(const float4*)&Bm[(long)(gn >> 6) * b_os + (long)(k0 + kk) * ldb + (gn & 63)];
            *(float4*)&Bs[kk][n] = bv;
        }
        __syncthreads();
        #pragma unroll
        for (int kk = 0; kk < 16; kk++) {
            float a8[8], b8[8];
            *(float4*)&a8[0] = *(const float4*)&As[kk][ty * 8];
            *(float4*)&a8[4] = *(const float4*)&As[kk][ty * 8 + 4];
            *(float4*)&b8[0] = *(const float4*)&Bs[kk][tx * 8];
            *(float4*)&b8[4] = *(const float4*)&Bs[kk][tx * 8 + 4];
            #pragma unroll
            for (int i = 0; i < 8; i++)
                #pragma unroll
                for (int j = 0; j < 8; j++)
                    acc[i][j] += a8[i] * b8[j];
        }
        __syncthreads();
    }

    #pragma unroll
    for (int i = 0; i < 8; i++) {
        int m = m0 + ty * 8 + i;
        #pragma unroll
        for (int j = 0; j < 8; j++) {
            int n = n0 + tx * 8 + j;
            float v = acc[i][j];
            if (BIAS) v += bias[n];
            if (RELU) v = fmaxf(v, 0.f);
            Cc[(long)m * ldc + n] = v;
        }
    }
}

// ---------------------------------------------------------------------------
// Flash-style causal attention, fp32.
// Block = (q-tile of 64 rows, head h, batch b), 256 threads.
// Thread (r = tid>>2, sub = tid&3): owns q-row r; scores for s in [sub*16,+16);
// output d-slice [sub*16,+16). Online softmax over s-tiles of 64.
// q/k/v buffers are [BT][C] with head h at column h*64.
// ---------------------------------------------------------------------------
__global__ __launch_bounds__(256) void attn_kernel(
    const float* __restrict__ qb, const float* __restrict__ kb,
    const float* __restrict__ vb, float* __restrict__ ob)
{
    const int qt = blockIdx.x, h = blockIdx.y, b = blockIdx.z;
    const int tid = threadIdx.x;
    const int r = tid >> 2;          // 0..63
    const int sub = tid & 3;         // 0..3
    const int rl = (tid & 63) >> 2;  // row-local within wave, 0..15

    __shared__ float Qs[64][68];
    __shared__ float Kt[64][68];
    __shared__ float Vt[64][68];

    const float* qbase = qb + ((long)(b * T_ + qt * 64)) * C_ + h * HS_;
    #pragma unroll
    for (int i = 0; i < 4; i++) {
        int f = tid + i * 256;       // 0..1023 float4 slots
        int rr = f >> 4, d = (f & 15) * 4;
        *(float4*)&Qs[rr][d] = *(const float4*)&qbase[(long)rr * C_ + d];
    }
    __syncthreads();

    float4 qreg[16];
    #pragma unroll
    for (int i = 0; i < 16; i++) qreg[i] = *(const float4*)&Qs[r][i * 4];

    float m = -3.0e38f, l = 0.f;
    float4 o4[4];
    #pragma unroll
    for (int j = 0; j < 4; j++) o4[j] = make_float4(0.f, 0.f, 0.f, 0.f);

    const int qg = qt * 64 + r;

    for (int st = 0; st <= qt; st++) {
        __syncthreads();   // protect Kt/Vt from previous iteration's readers
        const float* kbase = kb + ((long)(b * T_ + st * 64)) * C_ + h * HS_;
        const float* vbase = vb + ((long)(b * T_ + st * 64)) * C_ + h * HS_;
        #pragma unroll
        for (int i = 0; i < 4; i++) {
            int f = tid + i * 256;
            int rr = f >> 4, d = (f & 15) * 4;
            *(float4*)&Kt[rr][d] = *(const float4*)&kbase[(long)rr * C_ + d];
            *(float4*)&Vt[rr][d] = *(const float4*)&vbase[(long)rr * C_ + d];
        }
        __syncthreads();

        // scores for my 16 s values
        float p[16];
        float tmax = -3.0e38f;
        #pragma unroll
        for (int i = 0; i < 16; i++) {
            int s = sub * 16 + i;
            float acc = 0.f;
            #pragma unroll
            for (int d4 = 0; d4 < 16; d4++) {
                float4 kv = *(const float4*)&Kt[s][d4 * 4];
                acc += qreg[d4].x * kv.x + qreg[d4].y * kv.y
                     + qreg[d4].z * kv.z + qreg[d4].w * kv.w;
            }
            acc *= 0.125f;                       // HS^-0.5
            if (st * 64 + s > qg) acc = -1e30f;  // causal mask
            p[i] = acc;
            tmax = fmaxf(tmax, acc);
        }
        // row reduce (4 lanes per row)
        tmax = fmaxf(tmax, __shfl_xor(tmax, 1));
        tmax = fmaxf(tmax, __shfl_xor(tmax, 2));
        float mn = fmaxf(m, tmax);
        float scale = __expf(m - mn);
        float ps = 0.f;
        #pragma unroll
        for (int i = 0; i < 16; i++) { p[i] = __expf(p[i] - mn); ps += p[i]; }
        ps += __shfl_xor(ps, 1);
        ps += __shfl_xor(ps, 2);
        l = l * scale + ps;
        m = mn;
        #pragma unroll
        for (int j = 0; j < 4; j++) {
            o4[j].x *= scale; o4[j].y *= scale; o4[j].z *= scale; o4[j].w *= scale;
        }
        // PV: need p for all 64 s of my row -> shuffle from row-mates
        #pragma unroll
        for (int g = 0; g < 4; g++) {
            #pragma unroll
            for (int i = 0; i < 16; i++) {
                float pv = __shfl(p[i], rl * 4 + g);
                int s = g * 16 + i;
                #pragma unroll
                for (int j = 0; j < 4; j++) {
                    float4 vv = *(const float4*)&Vt[s][sub * 16 + j * 4];
                    o4[j].x += pv * vv.x; o4[j].y += pv * vv.y;
                    o4[j].z += pv * vv.z; o4[j].w += pv * vv.w;
                }
            }
        }
    }

    float inv = 1.f / l;
    float* obase = ob + ((long)(b * T_ + qg)) * C_ + h * HS_ + sub * 16;
    #pragma unroll
    for (int j = 0; j < 4; j++) {
        float4 v = o4[j];
        v.x *= inv; v.y *= inv; v.z *= inv; v.w *= inv;
        *(float4*)&obase[j * 4] = v;
    }
}

// ---------------------------------------------------------------------------
// Fused residual + LayerNorm over rows of C_=1024. out = LN(a + b)*g + beta
// ---------------------------------------------------------------------------
__global__ __launch_bounds__(256) void ln_kernel(
    const float* __restrict__ a, const float* __restrict__ bsrc,
    const float* __restrict__ g, const float* __restrict__ be,
    float* __restrict__ out)
{
    const long row = blockIdx.x;
    const float* pa = a + row * C_;
    const float* pb = bsrc + row * C_;
    float* po = out + row * C_;
    const int tid = threadIdx.x;

    float v[4];
    float s = 0.f;
    #pragma unroll
    for (int i = 0; i < 4; i++) {
        int idx = tid + i * 256;
        v[i] = pa[idx] + pb[idx];
        s += v[i];
    }
    #pragma unroll
    for (int off = 32; off > 0; off >>= 1) s += __shfl_down(s, off);
    __shared__ float red[4], red2[4];
    const int wid = tid >> 6, lane = tid & 63;
    if (lane == 0) red[wid] = s;
    __syncthreads();
    float mean = (red[0] + red[1] + red[2] + red[3]) * (1.f / 1024.f);

    float vs = 0.f;
    #pragma unroll
    for (int i = 0; i < 4; i++) { float d = v[i] - mean; vs += d * d; }
    #pragma unroll
    for (int off = 32; off > 0; off >>= 1) vs += __shfl_down(vs, off);
    if (lane == 0) red2[wid] = vs;
    __syncthreads();
    float var = (red2[0] + red2[1] + red2[2] + red2[3]) * (1.f / 1024.f);
    float rstd = rsqrtf(var + 1e-5f);

    #pragma unroll
    for (int i = 0; i < 4; i++) {
        int idx = tid + i * 256;
        po[idx] = (v[i] - mean) * rstd * g[idx] + be[idx];
    }
}

// ---------------------------------------------------------------------------
extern "C" void kernel_launch(void* const* d_in, const int* in_sizes, int n_in,
                              void* d_out, int out_size, void* d_ws, size_t ws_size,
                              hipStream_t stream) {
    const float* x     = (const float*)d_in[0];
    const float* wq    = (const float*)d_in[1];
    const float* wk    = (const float*)d_in[2];
    const float* wv    = (const float*)d_in[3];
    const float* wproj = (const float*)d_in[4];
    const float* bproj = (const float*)d_in[5];
    const float* ln1g  = (const float*)d_in[6];
    const float* ln1b  = (const float*)d_in[7];
    const float* w1    = (const float*)d_in[8];
    const float* b1    = (const float*)d_in[9];
    const float* w2    = (const float*)d_in[10];
    const float* b2    = (const float*)d_in[11];
    const float* ln2g  = (const float*)d_in[12];
    const float* ln2b  = (const float*)d_in[13];
    float* out = (float*)d_out;
    float* ws  = (float*)d_ws;

    const long M4 = (long)BT_ * C_;      // 4M floats
    float* qb   = ws + 0 * M4;
    float* kb   = ws + 1 * M4;
    float* vb   = ws + 2 * M4;
    float* attn = ws + 3 * M4;
    float* sa   = ws + 4 * M4;
    float* x1   = ws + 5 * M4;
    float* ff   = ws + 6 * M4;
    float* hbuf = ws;                    // reuses qb..attn (16M floats) after proj

    dim3 blk(256);

    // QKV projections: M=4096, N=1024, K=1024; head-blocked B (b_os=C*HS, ldb=HS)
    dim3 gQ(C_ / 128, BT_ / 128);
    gemm_f32<false, false><<<gQ, blk, 0, stream>>>(x, C_, wq, HS_, (long)C_ * HS_, qb, C_, nullptr, BT_, C_, C_);
    gemm_f32<false, false><<<gQ, blk, 0, stream>>>(x, C_, wk, HS_, (long)C_ * HS_, kb, C_, nullptr, BT_, C_, C_);
    gemm_f32<false, false><<<gQ, blk, 0, stream>>>(x, C_, wv, HS_, (long)C_ * HS_, vb, C_, nullptr, BT_, C_, C_);

    // Attention
    attn_kernel<<<dim3(T_ / 64, H_, B_), blk, 0, stream>>>(qb, kb, vb, attn);

    // Output projection: sa = attn @ wproj + bproj
    gemm_f32<false, true><<<dim3(C_ / 128, BT_ / 128), blk, 0, stream>>>(
        attn, C_, wproj, C_, 64L, sa, C_, bproj, BT_, C_, C_);

    // x1 = LN(x + sa)
    ln_kernel<<<BT_, blk, 0, stream>>>(x, sa, ln1g, ln1b, x1);

    // h = relu(x1 @ w1 + b1): M=4096, N=4096, K=1024
    gemm_f32<true, true><<<dim3(FF_ / 128, BT_ / 128), blk, 0, stream>>>(
        x1, C_, w1, FF_, 64L, hbuf, FF_, b1, BT_, FF_, C_);

    // ff = h @ w2 + b2: M=4096, N=1024, K=4096
    gemm_f32<false, true><<<dim3(C_ / 128, BT_ / 128), blk, 0, stream>>>(
        hbuf, FF_, w2, C_, 64L, ff, C_, b2, BT_, C_, FF_);

    // out = LN(x1 + ff)
    ln_kernel<<<BT_, blk, 0, stream>>>(x1, ff, ln2g, ln2b, out);
}

// Round 2
// 411.756 us; speedup vs baseline: 6.6668x; 6.6668x over previous
//
#include <hip/hip_runtime.h>

#define B_  2
#define T_  2048
#define C_  1024
#define H_  16
#define HS_ 64
#define FF_ 4096
#define BT_ 4096
#define LDQKV 3072

typedef __bf16 bf16x8 __attribute__((ext_vector_type(8)));
typedef float f32x4 __attribute__((ext_vector_type(4)));

__device__ __forceinline__ unsigned short f2bf(float f) {
    unsigned int u = __float_as_uint(f);
    u = (u + 0x7FFFu + ((u >> 16) & 1u)) >> 16;   // RNE
    return (unsigned short)u;
}
__device__ __forceinline__ float bf2f(unsigned short b) {
    return __uint_as_float(((unsigned int)b) << 16);
}

__device__ __forceinline__ void gload16(const void* g, void* l) {
    __builtin_amdgcn_global_load_lds(
        (const __attribute__((address_space(1))) void*)g,
        (__attribute__((address_space(3))) void*)l, 16, 0, 0);
}

// ---------------------------------------------------------------------------
// Tiled transpose + f32->bf16. out[n*K + k] = in[(n>>6)*b_os + k*ldb + (n&63)]
// Handles plain row-major [K][N] (b_os=64, ldb=N) and head-blocked (H,C,HS).
// ---------------------------------------------------------------------------
__global__ __launch_bounds__(256) void transpose_bf16(
    const float* __restrict__ in, int ldb, long b_os,
    unsigned short* __restrict__ out, int K, int N)
{
    __shared__ float t[32][33];
    const int k0 = blockIdx.x * 32, n0 = blockIdx.y * 32;
    const int tx = threadIdx.x & 31, ty = threadIdx.x >> 5;
    #pragma unroll
    for (int i = 0; i < 4; i++) {
        int k = k0 + ty + i * 8;
        int n = n0 + tx;
        t[ty + i * 8][tx] = in[(long)(n >> 6) * b_os + (long)k * ldb + (n & 63)];
    }
    __syncthreads();
    #pragma unroll
    for (int i = 0; i < 4; i++) {
        int n = n0 + ty + i * 8;
        out[(long)n * K + k0 + tx] = f2bf(t[tx][ty + i * 8]);
    }
}

__global__ __launch_bounds__(256) void convert_bf16_k(
    const float* __restrict__ in, unsigned short* __restrict__ out)
{
    int i = blockIdx.x * 256 + threadIdx.x;
    float4 v = ((const float4*)in)[i];
    ushort4 o;
    o.x = f2bf(v.x); o.y = f2bf(v.y); o.z = f2bf(v.z); o.w = f2bf(v.w);
    ((ushort4*)out)[i] = o;
}

// ---------------------------------------------------------------------------
// bf16 MFMA GEMM, m97 structure: 128x128 tile, BK=32, 4 waves (2x2), each wave
// 64x64 out = 4x4 frags of 16x16x32. A[M][K], Bt[N][K] (B transposed), bf16.
// ---------------------------------------------------------------------------
template<bool RELU, bool BIAS, bool OUT_BF16>
__global__ __launch_bounds__(256) void gemm_mfma(
    const unsigned short* __restrict__ A, const unsigned short* __restrict__ Bt,
    void* __restrict__ Cc, const float* __restrict__ bias,
    int M, int N, int K)
{
    __shared__ __align__(16) unsigned short As[128 * 32];
    __shared__ __align__(16) unsigned short Bs[128 * 32];
    const int tid = threadIdx.x;
    const int w = tid >> 6, l = tid & 63;
    const int fr = l & 15, fq = l >> 4;
    const int m0 = blockIdx.y * 128, n0 = blockIdx.x * 128;
    const int wm = (w >> 1) * 64, wn = (w & 1) * 64;

    f32x4 acc[4][4];
    #pragma unroll
    for (int m = 0; m < 4; m++)
        #pragma unroll
        for (int n = 0; n < 4; n++) acc[m][n] = (f32x4){0.f, 0.f, 0.f, 0.f};

    for (int k0 = 0; k0 < K; k0 += 32) {
        __syncthreads();
        #pragma unroll
        for (int i = 0; i < 2; i++) {
            int s = i * 256 + w * 64 + l;                 // segment 0..511
            gload16(&A[(long)(m0 + (s >> 2)) * K + k0 + (s & 3) * 8],
                    &As[(i * 256 + w * 64) * 8]);
            gload16(&Bt[(long)(n0 + (s >> 2)) * K + k0 + (s & 3) * 8],
                    &Bs[(i * 256 + w * 64) * 8]);
        }
        __syncthreads();
        bf16x8 a[4], b[4];
        #pragma unroll
        for (int m = 0; m < 4; m++)
            a[m] = *(const bf16x8*)&As[(wm + m * 16 + fr) * 32 + fq * 8];
        #pragma unroll
        for (int n = 0; n < 4; n++)
            b[n] = *(const bf16x8*)&Bs[(wn + n * 16 + fr) * 32 + fq * 8];
        #pragma unroll
        for (int m = 0; m < 4; m++)
            #pragma unroll
            for (int n = 0; n < 4; n++)
                acc[m][n] = __builtin_amdgcn_mfma_f32_16x16x32_bf16(
                    a[m], b[n], acc[m][n], 0, 0, 0);
    }

    #pragma unroll
    for (int m = 0; m < 4; m++) {
        #pragma unroll
        for (int n = 0; n < 4; n++) {
            int col = n0 + wn + n * 16 + fr;
            float bv = BIAS ? bias[col] : 0.f;
            #pragma unroll
            for (int j = 0; j < 4; j++) {
                long row = m0 + wm + m * 16 + fq * 4 + j;
                float v = acc[m][n][j] + bv;
                if (RELU) v = fmaxf(v, 0.f);
                if (OUT_BF16) ((unsigned short*)Cc)[row * N + col] = f2bf(v);
                else          ((float*)Cc)[row * N + col] = v;
            }
        }
    }
}

// ---------------------------------------------------------------------------
// MFMA flash attention. Block = (qt pair-swizzled, h, b), 4 waves x 16 q-rows.
// KV tile = 64. K staged via global_load_lds with XOR swizzle (src+read);
// V reg-staged transposed into Vt[d][s] (pad 72); S = mfma(Q,K); wave-parallel
// online softmax; P via per-wave LDS (pad 72) -> PV mfma.
// ---------------------------------------------------------------------------
__global__ __launch_bounds__(256) void attn_mfma(
    const unsigned short* __restrict__ qkv, unsigned short* __restrict__ ob)
{
    const int bx = blockIdx.x;
    const int qt = (bx & 1) ? (31 - (bx >> 1)) : (bx >> 1);   // load balance
    const int h = blockIdx.y, b = blockIdx.z;
    const int tid = threadIdx.x;
    const int w = tid >> 6, l = tid & 63;
    const int fr = l & 15, fq = l >> 4;

    __shared__ __align__(16) unsigned short Ks[64 * 64];      // swizzled
    __shared__ __align__(16) unsigned short Vt[64 * 72];      // V^T, padded
    __shared__ __align__(16) unsigned short Ps[4][16 * 72];   // per-wave P

    const long qrow = (long)(b * T_ + qt * 64 + w * 16 + fr);
    const bf16x8 qf0 = *(const bf16x8*)&qkv[qrow * LDQKV + h * 64 + fq * 8];
    const bf16x8 qf1 = *(const bf16x8*)&qkv[qrow * LDQKV + h * 64 + 32 + fq * 8];

    f32x4 oacc[4];
    float mj[4], lj[4];
    #pragma unroll
    for (int d = 0; d < 4; d++) oacc[d] = (f32x4){0.f, 0.f, 0.f, 0.f};
    #pragma unroll
    for (int j = 0; j < 4; j++) { mj[j] = -3.0e38f; lj[j] = 0.f; }

    for (int st = 0; st <= qt; st++) {
        __syncthreads();   // previous tile's LDS readers done
        // --- stage K (swizzled: phys 16B slot = logical slot ^ (row&7)) ---
        #pragma unroll
        for (int i = 0; i < 2; i++) {
            int s = i * 256 + w * 64 + l;       // 512 segs, 8 per 128B row
            int kr = s >> 3;
            int ke = ((s & 7) ^ (kr & 7)) * 8;  // pre-swizzled source column
            gload16(&qkv[(long)(b * T_ + st * 64 + kr) * LDQKV + 1024 + h * 64 + ke],
                    &Ks[(i * 256 + w * 64) * 8]);
        }
        // --- stage V transposed via registers ---
        #pragma unroll
        for (int i = 0; i < 2; i++) {
            int s = i * 256 + tid;
            int vr = s >> 3, vc = (s & 7) * 8;
            bf16x8 vv = *(const bf16x8*)&qkv[(long)(b * T_ + st * 64 + vr) * LDQKV + 2048 + h * 64 + vc];
            #pragma unroll
            for (int jj = 0; jj < 8; jj++)
                Vt[(vc + jj) * 72 + vr] = ((const unsigned short*)&vv)[jj];
        }
        __syncthreads();

        // --- S = Q K^T (per wave: 16q x 64s) ---
        f32x4 sacc[4];
        #pragma unroll
        for (int stile = 0; stile < 4; stile++) {
            sacc[stile] = (f32x4){0.f, 0.f, 0.f, 0.f};
            int krow = stile * 16 + fr;
            int rb = krow * 128;                       // byte row base
            int sw = (krow & 7) << 4;
            bf16x8 k0 = *(const bf16x8*)((const char*)Ks + rb + ((fq * 16) ^ sw));
            bf16x8 k1 = *(const bf16x8*)((const char*)Ks + rb + ((64 + fq * 16) ^ sw));
            sacc[stile] = __builtin_amdgcn_mfma_f32_16x16x32_bf16(qf0, k0, sacc[stile], 0, 0, 0);
            sacc[stile] = __builtin_amdgcn_mfma_f32_16x16x32_bf16(qf1, k1, sacc[stile], 0, 0, 0);
        }

        // --- masked online softmax (rows = fq*4+j, cols s = stile*16+fr) ---
        const int sbase = st * 64;
        const int qbase = qt * 64 + w * 16 + fq * 4;
        float pv[4][4];
        #pragma unroll
        for (int stile = 0; stile < 4; stile++)
            #pragma unroll
            for (int j = 0; j < 4; j++) {
                float v = sacc[stile][j] * 0.125f;
                if (sbase + stile * 16 + fr > qbase + j) v = -1e30f;
                pv[j][stile] = v;
            }
        #pragma unroll
        for (int j = 0; j < 4; j++) {
            float rm = fmaxf(fmaxf(pv[j][0], pv[j][1]), fmaxf(pv[j][2], pv[j][3]));
            rm = fmaxf(rm, __shfl_xor(rm, 1));
            rm = fmaxf(rm, __shfl_xor(rm, 2));
            rm = fmaxf(rm, __shfl_xor(rm, 4));
            rm = fmaxf(rm, __shfl_xor(rm, 8));
            float mn = fmaxf(mj[j], rm);
            float sc = __expf(mj[j] - mn);
            float rs = 0.f;
            #pragma unroll
            for (int stile = 0; stile < 4; stile++) {
                float p = __expf(pv[j][stile] - mn);
                rs += p;
                Ps[w][(fq * 4 + j) * 72 + stile * 16 + fr] = f2bf(p);
            }
            rs += __shfl_xor(rs, 1);
            rs += __shfl_xor(rs, 2);
            rs += __shfl_xor(rs, 4);
            rs += __shfl_xor(rs, 8);
            lj[j] = lj[j] * sc + rs;
            mj[j] = mn;
            oacc[0][j] *= sc; oacc[1][j] *= sc; oacc[2][j] *= sc; oacc[3][j] *= sc;
        }

        // --- O += P V (A = P from own wave's LDS, B = V^T rows) ---
        bf16x8 pf0 = *(const bf16x8*)&Ps[w][fr * 72 + fq * 8];
        bf16x8 pf1 = *(const bf16x8*)&Ps[w][fr * 72 + 32 + fq * 8];
        #pragma unroll
        for (int df = 0; df < 4; df++) {
            bf16x8 v0 = *(const bf16x8*)&Vt[(df * 16 + fr) * 72 + fq * 8];
            bf16x8 v1 = *(const bf16x8*)&Vt[(df * 16 + fr) * 72 + 32 + fq * 8];
            oacc[df] = __builtin_amdgcn_mfma_f32_16x16x32_bf16(pf0, v0, oacc[df], 0, 0, 0);
            oacc[df] = __builtin_amdgcn_mfma_f32_16x16x32_bf16(pf1, v1, oacc[df], 0, 0, 0);
        }
    }

    #pragma unroll
    for (int j = 0; j < 4; j++) {
        float inv = 1.f / lj[j];
        long orow = (long)(b * T_ + qt * 64 + w * 16 + fq * 4 + j);
        #pragma unroll
        for (int df = 0; df < 4; df++)
            ob[orow * C_ + h * 64 + df * 16 + fr] = f2bf(oacc[df][j] * inv);
    }
}

// ---------------------------------------------------------------------------
// Fused residual + LayerNorm: v = a(f32) + b(bf16); out f32 (+ optional bf16)
// ---------------------------------------------------------------------------
template<bool WB>
__global__ __launch_bounds__(256) void ln_fused(
    const float* __restrict__ a, const unsigned short* __restrict__ bsrc,
    const float* __restrict__ g, const float* __restrict__ be,
    float* __restrict__ outf, unsigned short* __restrict__ outb)
{
    const long row = blockIdx.x;
    const int tid = threadIdx.x;
    const float* pa = a + row * C_;
    const unsigned short* pb = bsrc + row * C_;

    float4 av = ((const float4*)pa)[tid];
    ushort4 bv = ((const ushort4*)pb)[tid];
    float v[4];
    v[0] = av.x + bf2f(bv.x); v[1] = av.y + bf2f(bv.y);
    v[2] = av.z + bf2f(bv.z); v[3] = av.w + bf2f(bv.w);

    float s = v[0] + v[1] + v[2] + v[3];
    #pragma unroll
    for (int off = 32; off > 0; off >>= 1) s += __shfl_down(s, off);
    __shared__ float red[4], red2[4];
    const int wid = tid >> 6, lane = tid & 63;
    if (lane == 0) red[wid] = s;
    __syncthreads();
    float mean = (red[0] + red[1] + red[2] + red[3]) * (1.f / 1024.f);

    float vs = 0.f;
    #pragma unroll
    for (int i = 0; i < 4; i++) { float d = v[i] - mean; vs += d * d; }
    #pragma unroll
    for (int off = 32; off > 0; off >>= 1) vs += __shfl_down(vs, off);
    if (lane == 0) red2[wid] = vs;
    __syncthreads();
    float var = (red2[0] + red2[1] + red2[2] + red2[3]) * (1.f / 1024.f);
    float rstd = rsqrtf(var + 1e-5f);

    float4 gv = ((const float4*)g)[tid];
    float4 ev = ((const float4*)be)[tid];
    float4 ov;
    ov.x = (v[0] - mean) * rstd * gv.x + ev.x;
    ov.y = (v[1] - mean) * rstd * gv.y + ev.y;
    ov.z = (v[2] - mean) * rstd * gv.z + ev.z;
    ov.w = (v[3] - mean) * rstd * gv.w + ev.w;
    ((float4*)(outf + row * C_))[tid] = ov;
    if (WB) {
        ushort4 o;
        o.x = f2bf(ov.x); o.y = f2bf(ov.y); o.z = f2bf(ov.z); o.w = f2bf(ov.w);
        ((ushort4*)(outb + row * C_))[tid] = o;
    }
}

// ---------------------------------------------------------------------------
extern "C" void kernel_launch(void* const* d_in, const int* in_sizes, int n_in,
                              void* d_out, int out_size, void* d_ws, size_t ws_size,
                              hipStream_t stream) {
    const float* x     = (const float*)d_in[0];
    const float* wq    = (const float*)d_in[1];
    const float* wk    = (const float*)d_in[2];
    const float* wv    = (const float*)d_in[3];
    const float* wproj = (const float*)d_in[4];
    const float* bproj = (const float*)d_in[5];
    const float* ln1g  = (const float*)d_in[6];
    const float* ln1b  = (const float*)d_in[7];
    const float* w1    = (const float*)d_in[8];
    const float* b1    = (const float*)d_in[9];
    const float* w2    = (const float*)d_in[10];
    const float* b2    = (const float*)d_in[11];
    const float* ln2g  = (const float*)d_in[12];
    const float* ln2b  = (const float*)d_in[13];
    float* out = (float*)d_out;

    char* wsb = (char*)d_ws;
    unsigned short* xb     = (unsigned short*)(wsb);                 // [0,8MB)
    unsigned short* wqkvt  = (unsigned short*)(wsb + (8L  << 20));   // [8,14)
    unsigned short* wprojt = (unsigned short*)(wsb + (14L << 20));   // [14,16)
    unsigned short* w1t    = (unsigned short*)(wsb + (16L << 20));   // [16,24)
    unsigned short* w2t    = (unsigned short*)(wsb + (24L << 20));   // [24,32)
    unsigned short* qkv    = (unsigned short*)(wsb + (32L << 20));   // [32,56)
    unsigned short* attnb  = (unsigned short*)(wsb + (56L << 20));   // [56,64)
    unsigned short* sab    = (unsigned short*)(wsb + (64L << 20));   // [64,72)
    float*          x1f    = (float*)(wsb + (72L << 20));            // [72,88)
    unsigned short* x1b    = (unsigned short*)(wsb + (88L << 20));   // [88,96)
    unsigned short* hb     = (unsigned short*)(wsb + (32L << 20));   // reuse [32,64)
    unsigned short* ffb    = (unsigned short*)(wsb + (64L << 20));   // reuse [64,72)

    dim3 blk(256);

    // bf16 conversions / weight transposes (B^T layout [N][K])
    convert_bf16_k<<<BT_ * C_ / 1024, blk, 0, stream>>>(x, xb);
    transpose_bf16<<<dim3(32, 32),  blk, 0, stream>>>(wq,    HS_, (long)C_ * HS_, wqkvt,                C_, C_);
    transpose_bf16<<<dim3(32, 32),  blk, 0, stream>>>(wk,    HS_, (long)C_ * HS_, wqkvt + 1024 * 1024,  C_, C_);
    transpose_bf16<<<dim3(32, 32),  blk, 0, stream>>>(wv,    HS_, (long)C_ * HS_, wqkvt + 2048 * 1024,  C_, C_);
    transpose_bf16<<<dim3(32, 32),  blk, 0, stream>>>(wproj, C_,  64L,            wprojt,               C_, C_);
    transpose_bf16<<<dim3(32, 128), blk, 0, stream>>>(w1,    FF_, 64L,            w1t,                  C_, FF_);
    transpose_bf16<<<dim3(128, 32), blk, 0, stream>>>(w2,    C_,  64L,            w2t,                  FF_, C_);

    // fused QKV projection: [4096,3072] = xb @ wqkvt^T
    gemm_mfma<false, false, true><<<dim3(24, 32), blk, 0, stream>>>(
        xb, wqkvt, qkv, nullptr, BT_, LDQKV, C_);

    // attention
    attn_mfma<<<dim3(32, 16, 2), blk, 0, stream>>>(qkv, attnb);

    // output projection (+bias)
    gemm_mfma<false, true, true><<<dim3(8, 32), blk, 0, stream>>>(
        attnb, wprojt, sab, bproj, BT_, C_, C_);

    // x1 = LN(x + sa) -> f32 + bf16
    ln_fused<true><<<BT_, blk, 0, stream>>>(x, sab, ln1g, ln1b, x1f, x1b);

    // h = relu(x1 @ w1 + b1)
    gemm_mfma<true, true, true><<<dim3(32, 32), blk, 0, stream>>>(
        x1b, w1t, hb, b1, BT_, FF_, C_);

    // ff = h @ w2 + b2
    gemm_mfma<false, true, true><<<dim3(8, 32), blk, 0, stream>>>(
        hb, w2t, ffb, b2, BT_, C_, FF_);

    // out = LN(x1 + ff)
    ln_fused<false><<<BT_, blk, 0, stream>>>(x1f, ffb, ln2g, ln2b, out, nullptr);
}

// Round 4
// 411.289 us; speedup vs baseline: 6.6744x; 1.0011x over previous
//
#include <hip/hip_runtime.h>

#define B_  2
#define T_  2048
#define C_  1024
#define H_  16
#define HS_ 64
#define FF_ 4096
#define BT_ 4096
#define LDQKV 3072

typedef __bf16 bf16x8 __attribute__((ext_vector_type(8)));
typedef float f32x4 __attribute__((ext_vector_type(4)));

__device__ __forceinline__ unsigned short f2bf(float f) {
    unsigned int u = __float_as_uint(f);
    u = (u + 0x7FFFu + ((u >> 16) & 1u)) >> 16;   // RNE
    return (unsigned short)u;
}
__device__ __forceinline__ float bf2f(unsigned short b) {
    return __uint_as_float(((unsigned int)b) << 16);
}

__device__ __forceinline__ void gload16(const void* g, void* l) {
    __builtin_amdgcn_global_load_lds(
        (const __attribute__((address_space(1))) void*)g,
        (__attribute__((address_space(3))) void*)l, 16, 0, 0);
}

// ---------------------------------------------------------------------------
// Tiled transpose + f32->bf16. out[n*K + k] = in[(n>>6)*b_os + k*ldb + (n&63)]
// ---------------------------------------------------------------------------
__global__ __launch_bounds__(256) void transpose_bf16(
    const float* __restrict__ in, int ldb, long b_os,
    unsigned short* __restrict__ out, int K, int N)
{
    __shared__ float t[32][33];
    const int k0 = blockIdx.x * 32, n0 = blockIdx.y * 32;
    const int tx = threadIdx.x & 31, ty = threadIdx.x >> 5;
    #pragma unroll
    for (int i = 0; i < 4; i++) {
        int k = k0 + ty + i * 8;
        int n = n0 + tx;
        t[ty + i * 8][tx] = in[(long)(n >> 6) * b_os + (long)k * ldb + (n & 63)];
    }
    __syncthreads();
    #pragma unroll
    for (int i = 0; i < 4; i++) {
        int n = n0 + ty + i * 8;
        out[(long)n * K + k0 + tx] = f2bf(t[tx][ty + i * 8]);
    }
}

__global__ __launch_bounds__(256) void convert_bf16_k(
    const float* __restrict__ in, unsigned short* __restrict__ out)
{
    int i = blockIdx.x * 256 + threadIdx.x;
    float4 v = ((const float4*)in)[i];
    ushort4 o;
    o.x = f2bf(v.x); o.y = f2bf(v.y); o.z = f2bf(v.z); o.w = f2bf(v.w);
    ((ushort4*)out)[i] = o;
}

// ---------------------------------------------------------------------------
// bf16 MFMA GEMM, m97 structure (unchanged from round 2)
// ---------------------------------------------------------------------------
template<bool RELU, bool BIAS, bool OUT_BF16>
__global__ __launch_bounds__(256) void gemm_mfma(
    const unsigned short* __restrict__ A, const unsigned short* __restrict__ Bt,
    void* __restrict__ Cc, const float* __restrict__ bias,
    int M, int N, int K)
{
    __shared__ __align__(16) unsigned short As[128 * 32];
    __shared__ __align__(16) unsigned short Bs[128 * 32];
    const int tid = threadIdx.x;
    const int w = tid >> 6, l = tid & 63;
    const int fr = l & 15, fq = l >> 4;
    const int m0 = blockIdx.y * 128, n0 = blockIdx.x * 128;
    const int wm = (w >> 1) * 64, wn = (w & 1) * 64;

    f32x4 acc[4][4];
    #pragma unroll
    for (int m = 0; m < 4; m++)
        #pragma unroll
        for (int n = 0; n < 4; n++) acc[m][n] = (f32x4){0.f, 0.f, 0.f, 0.f};

    for (int k0 = 0; k0 < K; k0 += 32) {
        __syncthreads();
        #pragma unroll
        for (int i = 0; i < 2; i++) {
            int s = i * 256 + w * 64 + l;
            gload16(&A[(long)(m0 + (s >> 2)) * K + k0 + (s & 3) * 8],
                    &As[(i * 256 + w * 64) * 8]);
            gload16(&Bt[(long)(n0 + (s >> 2)) * K + k0 + (s & 3) * 8],
                    &Bs[(i * 256 + w * 64) * 8]);
        }
        __syncthreads();
        bf16x8 a[4], b[4];
        #pragma unroll
        for (int m = 0; m < 4; m++)
            a[m] = *(const bf16x8*)&As[(wm + m * 16 + fr) * 32 + fq * 8];
        #pragma unroll
        for (int n = 0; n < 4; n++)
            b[n] = *(const bf16x8*)&Bs[(wn + n * 16 + fr) * 32 + fq * 8];
        __builtin_amdgcn_s_setprio(1);
        #pragma unroll
        for (int m = 0; m < 4; m++)
            #pragma unroll
            for (int n = 0; n < 4; n++)
                acc[m][n] = __builtin_amdgcn_mfma_f32_16x16x32_bf16(
                    a[m], b[n], acc[m][n], 0, 0, 0);
        __builtin_amdgcn_s_setprio(0);
    }

    #pragma unroll
    for (int m = 0; m < 4; m++) {
        #pragma unroll
        for (int n = 0; n < 4; n++) {
            int col = n0 + wn + n * 16 + fr;
            float bv = BIAS ? bias[col] : 0.f;
            #pragma unroll
            for (int j = 0; j < 4; j++) {
                long row = m0 + wm + m * 16 + fq * 4 + j;
                float v = acc[m][n][j] + bv;
                if (RELU) v = fmaxf(v, 0.f);
                if (OUT_BF16) ((unsigned short*)Cc)[row * N + col] = f2bf(v);
                else          ((float*)Cc)[row * N + col] = v;
            }
        }
    }
}

// ---------------------------------------------------------------------------
// MFMA flash attention, round 4:
//   = round 2's PROVEN data paths (K XOR-swizzle via gload_lds; V register-
//     transpose into padded Vt[64][72]; Ps per-wave; round-2 PV reads)
//   + double-buffering: K prefetch via gload_lds into Ks[cur^1] at tile start;
//     V prefetch into registers (issue-early), ds_write-transpose after PV;
//     ONE __syncthreads per tile (drains vmcnt + lgkmcnt, releases buffers).
//   + setprio(1) around MFMA clusters.
// ---------------------------------------------------------------------------
__global__ __launch_bounds__(256) void attn_mfma(
    const unsigned short* __restrict__ qkv, unsigned short* __restrict__ ob)
{
    const int bx = blockIdx.x;
    const int qt = (bx & 1) ? (31 - (bx >> 1)) : (bx >> 1);   // load balance
    const int h = blockIdx.y, b = blockIdx.z;
    const int tid = threadIdx.x;
    const int w = tid >> 6, l = tid & 63;
    const int fr = l & 15, fq = l >> 4;

    __shared__ __align__(16) unsigned short Ks[2][64 * 64];   // K, XOR-swizzled
    __shared__ __align__(16) unsigned short Vt[2][64 * 72];   // V^T, padded
    __shared__ __align__(16) unsigned short Ps[4][16 * 72];   // per-wave P

    const long qrow = (long)(b * T_ + qt * 64 + w * 16 + fr);
    const bf16x8 qf0 = *(const bf16x8*)&qkv[qrow * LDQKV + h * 64 + fq * 8];
    const bf16x8 qf1 = *(const bf16x8*)&qkv[qrow * LDQKV + h * 64 + 32 + fq * 8];

    // staging source positions (per thread, both 256-seg groups)
    int kr[2], keo[2], vr[2], vc[2];
    #pragma unroll
    for (int i = 0; i < 2; i++) {
        int g = i * 256 + tid;
        kr[i]  = g >> 3;
        keo[i] = ((g & 7) ^ (kr[i] & 7)) * 8;   // K column pre-swizzle
        vr[i]  = g >> 3;                        // V row (s)
        vc[i]  = (g & 7) * 8;                   // V col base (d)
    }

    f32x4 oacc[4];
    float mj[4], lj[4];
    #pragma unroll
    for (int d = 0; d < 4; d++) oacc[d] = (f32x4){0.f, 0.f, 0.f, 0.f};
    #pragma unroll
    for (int j = 0; j < 4; j++) { mj[j] = -3.0e38f; lj[j] = 0.f; }

    const unsigned short* kb0 = qkv + (long)b * T_ * LDQKV + 1024 + h * 64;
    const unsigned short* vb0 = qkv + (long)b * T_ * LDQKV + 2048 + h * 64;

    // ---- prologue: stage tile 0 into buffer 0 ----
    #pragma unroll
    for (int i = 0; i < 2; i++)
        gload16(kb0 + (long)kr[i] * LDQKV + keo[i], &Ks[0][(i * 256 + w * 64) * 8]);
    {
        bf16x8 v0[2];
        #pragma unroll
        for (int i = 0; i < 2; i++)
            v0[i] = *(const bf16x8*)&vb0[(long)vr[i] * LDQKV + vc[i]];
        #pragma unroll
        for (int i = 0; i < 2; i++)
            #pragma unroll
            for (int jj = 0; jj < 8; jj++)
                Vt[0][(vc[i] + jj) * 72 + vr[i]] = ((const unsigned short*)&v0[i])[jj];
    }
    __syncthreads();

    for (int st = 0; st <= qt; st++) {
        const int cur = st & 1;
        const int nxt = cur ^ 1;

        // ---- prefetch next tile: K direct to LDS, V to registers ----
        bf16x8 vnext[2];
        if (st < qt) {
            const unsigned short* kb = kb0 + (long)(st + 1) * 64 * LDQKV;
            const unsigned short* vb = vb0 + (long)(st + 1) * 64 * LDQKV;
            #pragma unroll
            for (int i = 0; i < 2; i++) {
                gload16(kb + (long)kr[i] * LDQKV + keo[i], &Ks[nxt][(i * 256 + w * 64) * 8]);
                vnext[i] = *(const bf16x8*)&vb[(long)vr[i] * LDQKV + vc[i]];
            }
        }

        // ---- S = Q K^T (per wave: 16q x 64s) ----
        f32x4 sacc[4];
        {
            bf16x8 k0v[4], k1v[4];
            #pragma unroll
            for (int stile = 0; stile < 4; stile++) {
                int krow = stile * 16 + fr;
                int rb = krow * 128;
                int sw = (krow & 7) << 4;
                k0v[stile] = *(const bf16x8*)((const char*)Ks[cur] + rb + ((fq * 16) ^ sw));
                k1v[stile] = *(const bf16x8*)((const char*)Ks[cur] + rb + ((64 + fq * 16) ^ sw));
            }
            __builtin_amdgcn_s_setprio(1);
            #pragma unroll
            for (int stile = 0; stile < 4; stile++) {
                sacc[stile] = (f32x4){0.f, 0.f, 0.f, 0.f};
                sacc[stile] = __builtin_amdgcn_mfma_f32_16x16x32_bf16(qf0, k0v[stile], sacc[stile], 0, 0, 0);
                sacc[stile] = __builtin_amdgcn_mfma_f32_16x16x32_bf16(qf1, k1v[stile], sacc[stile], 0, 0, 0);
            }
            __builtin_amdgcn_s_setprio(0);
        }

        // ---- masked online softmax (rows fq*4+j, cols s = stile*16+fr) ----
        const int sbase = st * 64;
        const int qbase = qt * 64 + w * 16 + fq * 4;
        float pv[4][4];
        #pragma unroll
        for (int stile = 0; stile < 4; stile++)
            #pragma unroll
            for (int j = 0; j < 4; j++) {
                float v = sacc[stile][j] * 0.125f;
                if (sbase + stile * 16 + fr > qbase + j) v = -1e30f;
                pv[j][stile] = v;
            }
        #pragma unroll
        for (int j = 0; j < 4; j++) {
            float rm = fmaxf(fmaxf(pv[j][0], pv[j][1]), fmaxf(pv[j][2], pv[j][3]));
            rm = fmaxf(rm, __shfl_xor(rm, 1));
            rm = fmaxf(rm, __shfl_xor(rm, 2));
            rm = fmaxf(rm, __shfl_xor(rm, 4));
            rm = fmaxf(rm, __shfl_xor(rm, 8));
            float mn = fmaxf(mj[j], rm);
            float sc = __expf(mj[j] - mn);
            float rs = 0.f;
            #pragma unroll
            for (int stile = 0; stile < 4; stile++) {
                float p = __expf(pv[j][stile] - mn);
                rs += p;
                Ps[w][(fq * 4 + j) * 72 + stile * 16 + fr] = f2bf(p);
            }
            rs += __shfl_xor(rs, 1);
            rs += __shfl_xor(rs, 2);
            rs += __shfl_xor(rs, 4);
            rs += __shfl_xor(rs, 8);
            lj[j] = lj[j] * sc + rs;
            mj[j] = mn;
            oacc[0][j] *= sc; oacc[1][j] *= sc; oacc[2][j] *= sc; oacc[3][j] *= sc;
        }

        // ---- O += P V (A = P from own wave's LDS, B = V^T rows) ----
        {
            bf16x8 pf0 = *(const bf16x8*)&Ps[w][fr * 72 + fq * 8];
            bf16x8 pf1 = *(const bf16x8*)&Ps[w][fr * 72 + 32 + fq * 8];
            __builtin_amdgcn_s_setprio(1);
            #pragma unroll
            for (int df = 0; df < 4; df++) {
                bf16x8 v0 = *(const bf16x8*)&Vt[cur][(df * 16 + fr) * 72 + fq * 8];
                bf16x8 v1 = *(const bf16x8*)&Vt[cur][(df * 16 + fr) * 72 + 32 + fq * 8];
                oacc[df] = __builtin_amdgcn_mfma_f32_16x16x32_bf16(pf0, v0, oacc[df], 0, 0, 0);
                oacc[df] = __builtin_amdgcn_mfma_f32_16x16x32_bf16(pf1, v1, oacc[df], 0, 0, 0);
            }
            __builtin_amdgcn_s_setprio(0);
        }

        // ---- write prefetched V (transpose) into next buffer ----
        if (st < qt) {
            #pragma unroll
            for (int i = 0; i < 2; i++)
                #pragma unroll
                for (int jj = 0; jj < 8; jj++)
                    Vt[nxt][(vc[i] + jj) * 72 + vr[i]] = ((const unsigned short*)&vnext[i])[jj];
        }

        __syncthreads();   // drains K prefetch vmcnt + V ds_writes, releases buffers
    }

    #pragma unroll
    for (int j = 0; j < 4; j++) {
        float inv = 1.f / lj[j];
        long orow = (long)(b * T_ + qt * 64 + w * 16 + fq * 4 + j);
        #pragma unroll
        for (int df = 0; df < 4; df++)
            ob[orow * C_ + h * 64 + df * 16 + fr] = f2bf(oacc[df][j] * inv);
    }
}

// ---------------------------------------------------------------------------
// Fused residual + LayerNorm
// ---------------------------------------------------------------------------
template<bool WB>
__global__ __launch_bounds__(256) void ln_fused(
    const float* __restrict__ a, const unsigned short* __restrict__ bsrc,
    const float* __restrict__ g, const float* __restrict__ be,
    float* __restrict__ outf, unsigned short* __restrict__ outb)
{
    const long row = blockIdx.x;
    const int tid = threadIdx.x;
    const float* pa = a + row * C_;
    const unsigned short* pb = bsrc + row * C_;

    float4 av = ((const float4*)pa)[tid];
    ushort4 bv = ((const ushort4*)pb)[tid];
    float v[4];
    v[0] = av.x + bf2f(bv.x); v[1] = av.y + bf2f(bv.y);
    v[2] = av.z + bf2f(bv.z); v[3] = av.w + bf2f(bv.w);

    float s = v[0] + v[1] + v[2] + v[3];
    #pragma unroll
    for (int off = 32; off > 0; off >>= 1) s += __shfl_down(s, off);
    __shared__ float red[4], red2[4];
    const int wid = tid >> 6, lane = tid & 63;
    if (lane == 0) red[wid] = s;
    __syncthreads();
    float mean = (red[0] + red[1] + red[2] + red[3]) * (1.f / 1024.f);

    float vs = 0.f;
    #pragma unroll
    for (int i = 0; i < 4; i++) { float d = v[i] - mean; vs += d * d; }
    #pragma unroll
    for (int off = 32; off > 0; off >>= 1) vs += __shfl_down(vs, off);
    if (lane == 0) red2[wid] = vs;
    __syncthreads();
    float var = (red2[0] + red2[1] + red2[2] + red2[3]) * (1.f / 1024.f);
    float rstd = rsqrtf(var + 1e-5f);

    float4 gv = ((const float4*)g)[tid];
    float4 ev = ((const float4*)be)[tid];
    float4 ov;
    ov.x = (v[0] - mean) * rstd * gv.x + ev.x;
    ov.y = (v[1] - mean) * rstd * gv.y + ev.y;
    ov.z = (v[2] - mean) * rstd * gv.z + ev.z;
    ov.w = (v[3] - mean) * rstd * gv.w + ev.w;
    ((float4*)(outf + row * C_))[tid] = ov;
    if (WB) {
        ushort4 o;
        o.x = f2bf(ov.x); o.y = f2bf(ov.y); o.z = f2bf(ov.z); o.w = f2bf(ov.w);
        ((ushort4*)(outb + row * C_))[tid] = o;
    }
}

// ---------------------------------------------------------------------------
extern "C" void kernel_launch(void* const* d_in, const int* in_sizes, int n_in,
                              void* d_out, int out_size, void* d_ws, size_t ws_size,
                              hipStream_t stream) {
    const float* x     = (const float*)d_in[0];
    const float* wq    = (const float*)d_in[1];
    const float* wk    = (const float*)d_in[2];
    const float* wv    = (const float*)d_in[3];
    const float* wproj = (const float*)d_in[4];
    const float* bproj = (const float*)d_in[5];
    const float* ln1g  = (const float*)d_in[6];
    const float* ln1b  = (const float*)d_in[7];
    const float* w1    = (const float*)d_in[8];
    const float* b1    = (const float*)d_in[9];
    const float* w2    = (const float*)d_in[10];
    const float* b2    = (const float*)d_in[11];
    const float* ln2g  = (const float*)d_in[12];
    const float* ln2b  = (const float*)d_in[13];
    float* out = (float*)d_out;

    char* wsb = (char*)d_ws;
    unsigned short* xb     = (unsigned short*)(wsb);                 // [0,8MB)
    unsigned short* wqkvt  = (unsigned short*)(wsb + (8L  << 20));   // [8,14)
    unsigned short* wprojt = (unsigned short*)(wsb + (14L << 20));   // [14,16)
    unsigned short* w1t    = (unsigned short*)(wsb + (16L << 20));   // [16,24)
    unsigned short* w2t    = (unsigned short*)(wsb + (24L << 20));   // [24,32)
    unsigned short* qkv    = (unsigned short*)(wsb + (32L << 20));   // [32,56)
    unsigned short* attnb  = (unsigned short*)(wsb + (56L << 20));   // [56,64)
    unsigned short* sab    = (unsigned short*)(wsb + (64L << 20));   // [64,72)
    float*          x1f    = (float*)(wsb + (72L << 20));            // [72,88)
    unsigned short* x1b    = (unsigned short*)(wsb + (88L << 20));   // [88,96)
    unsigned short* hb     = (unsigned short*)(wsb + (32L << 20));   // reuse [32,64)
    unsigned short* ffb    = (unsigned short*)(wsb + (64L << 20));   // reuse [64,72)

    dim3 blk(256);

    convert_bf16_k<<<BT_ * C_ / 1024, blk, 0, stream>>>(x, xb);
    transpose_bf16<<<dim3(32, 32),  blk, 0, stream>>>(wq,    HS_, (long)C_ * HS_, wqkvt,                C_, C_);
    transpose_bf16<<<dim3(32, 32),  blk, 0, stream>>>(wk,    HS_, (long)C_ * HS_, wqkvt + 1024 * 1024,  C_, C_);
    transpose_bf16<<<dim3(32, 32),  blk, 0, stream>>>(wv,    HS_, (long)C_ * HS_, wqkvt + 2048 * 1024,  C_, C_);
    transpose_bf16<<<dim3(32, 32),  blk, 0, stream>>>(wproj, C_,  64L,            wprojt,               C_, C_);
    transpose_bf16<<<dim3(32, 128), blk, 0, stream>>>(w1,    FF_, 64L,            w1t,                  C_, FF_);
    transpose_bf16<<<dim3(128, 32), blk, 0, stream>>>(w2,    C_,  64L,            w2t,                  FF_, C_);

    gemm_mfma<false, false, true><<<dim3(24, 32), blk, 0, stream>>>(
        xb, wqkvt, qkv, nullptr, BT_, LDQKV, C_);

    attn_mfma<<<dim3(32, 16, 2), blk, 0, stream>>>(qkv, attnb);

    gemm_mfma<false, true, true><<<dim3(8, 32), blk, 0, stream>>>(
        attnb, wprojt, sab, bproj, BT_, C_, C_);

    ln_fused<true><<<BT_, blk, 0, stream>>>(x, sab, ln1g, ln1b, x1f, x1b);

    gemm_mfma<true, true, true><<<dim3(32, 32), blk, 0, stream>>>(
        x1b, w1t, hb, b1, BT_, FF_, C_);

    gemm_mfma<false, true, true><<<dim3(8, 32), blk, 0, stream>>>(
        hb, w2t, ffb, b2, BT_, C_, FF_);

    ln_fused<false><<<BT_, blk, 0, stream>>>(x1f, ffb, ln2g, ln2b, out, nullptr);
}